// Round 2
// 260.358 us; speedup vs baseline: 1.0347x; 1.0347x over previous
//
#include <hip/hip_runtime.h>

// ChannelBlockImportanceGate: B=8, C=256, H=W=132, BLOCK=8, KEEP_RATIO=0.25
// Output = hard top-72 block mask (of 289 blocks) upsampled 8x, per (b,c) plane.
// Straight-through soft blend cancels numerically -> output is the hard mask.
//
// v2b: single barrier-free float4 streaming pass for block sums (fp64 LDS
// atomics, ds_add_f64), 3 barriers total (was 34), all 256 lanes loading
// 16B each (was 132 lanes x 4B). double2-vectorized rank loop. Nontemporal
// stores for the write-once output (via native vector type — HIP float4
// class is rejected by __builtin_nontemporal_store).

#define HH 132
#define WW 132
#define NB 17          // blocks per side (ceil(132/8) = 17)
#define TOTAL 289      // NB*NB
#define KEEP 72        // round(289*0.25)
#define NTHREADS 256
#define NV ((HH * WW) / 4)   // 4356 float4s per plane (132%4==0)

typedef float floatx4 __attribute__((ext_vector_type(4)));

__global__ __launch_bounds__(NTHREADS)
void gate_kernel(const float4* __restrict__ feats4,
                 const int* __restrict__ enabled_p,
                 float4* __restrict__ out4) {
    const int plane = blockIdx.x;            // b*C + c, 0..2047
    const int t = threadIdx.x;
    const float4* __restrict__ fp = feats4 + (size_t)plane * NV;
    floatx4* __restrict__ op = (floatx4*)(out4 + (size_t)plane * NV);

    // 290 doubles: pad one -inf entry so the rank loop can read double2.
    __shared__ __align__(16) double s_score[TOTAL + 1];
    __shared__ float s_hard[TOTAL];

    // ---- init ----
    for (int i = t; i < TOTAL + 1; i += NTHREADS)
        s_score[i] = (i < TOTAL) ? 0.0 : -1.0e300;
    __syncthreads();

    // ---- Phase 1: streaming block sums of |x| ----
    // float4 at 4-aligned col never crosses an 8-wide block boundary
    // (132 % 4 == 0), so each float4 maps to exactly one block.
    // fp64 accumulation: exact enough (~1e-15 rel) that atomic ordering
    // cannot perturb the ranking -> deterministic mask.
    for (int v = t; v < NV; v += NTHREADS) {
        const float4 x = fp[v];
        const double s = (double)fabsf(x.x) + (double)fabsf(x.y)
                       + (double)fabsf(x.z) + (double)fabsf(x.w);
        const int base = v * 4;
        const int row = base / WW;           // magic-mul division
        const int col = base - row * WW;
        atomicAdd(&s_score[(row >> 3) * NB + (col >> 3)], s);  // ds_add_f64
    }
    __syncthreads();

    // ---- Phase 2: top-72 by stable rank (matches lax.top_k ties) ----
    const int en = *enabled_p;
    const double2* __restrict__ sc2 = (const double2*)s_score;
    for (int i = t; i < TOTAL; i += NTHREADS) {
        const double si = s_score[i];
        int rank = 0;
        #pragma unroll 5
        for (int q = 0; q < (TOTAL + 1) / 2; ++q) {   // 145 double2 reads
            const double2 sj = sc2[q];
            const int j = q * 2;
            rank += (int)((sj.x > si) || ((sj.x == si) && (j < i)));
            rank += (int)((sj.y > si) || ((sj.y == si) && (j + 1 < i)));
        }
        s_hard[i] = (!en || rank < KEEP) ? 1.0f : 0.0f;
    }
    __syncthreads();

    // ---- Phase 3: upsample 8x, nontemporal float4 stores ----
    for (int v = t; v < NV; v += NTHREADS) {
        const int base = v * 4;
        const int row = base / WW;
        const int col = base - row * WW;
        const float m = s_hard[(row >> 3) * NB + (col >> 3)];
        const floatx4 mv = {m, m, m, m};
        __builtin_nontemporal_store(mv, &op[v]);
    }
}

extern "C" void kernel_launch(void* const* d_in, const int* in_sizes, int n_in,
                              void* d_out, int out_size, void* d_ws, size_t ws_size,
                              hipStream_t stream) {
    const float4* feats = (const float4*)d_in[0];
    const int* enabled = (const int*)d_in[1];
    float4* out = (float4*)d_out;
    const int planes = 8 * 256;              // B*C = 2048
    gate_kernel<<<planes, NTHREADS, 0, stream>>>(feats, enabled, out);
}